// Round 1
// baseline (1856.391 us; speedup 1.0000x reference)
//
#include <hip/hip_runtime.h>
#include <cstdint>
#include <cstddef>

#define NNODES 100000
#define FIN    512
#define HID    256
#define NCLS   64
#define KSTEPS 10
#define ALPHA  0.1f

#define NBUCK  1563     // ceil(NNODES/64)
#define BCAP   3072     // mean 2048, std ~45 -> 22 sigma headroom

// src-range partitioning for L2-resident propagation
#define NPARTS  4
#define PART_SZ 25000            // NNODES / NPARTS -> 3.2 MB of g per part (<= 4 MB XCD L2)
#define PCAP    808000           // per-part col region capacity: mean 800K + 10 sigma
#define NPW     25               // nodes per wave
#define PROPB   1000             // NNODES / (NPW*4 waves) exactly

typedef __bf16 bf16;
typedef __attribute__((ext_vector_type(4))) __bf16 bf16x4;
typedef __attribute__((ext_vector_type(8))) __bf16 bf16x8;
typedef __attribute__((ext_vector_type(4))) float f32x4;

// ---------------- transpose + f32->bf16 convert for weights ----------------
__global__ void transpose_bf16(const float* __restrict__ W, bf16* __restrict__ Wt,
                               int K, int N) {
  int idx = blockIdx.x * 256 + threadIdx.x;
  if (idx >= K * N) return;
  int k = idx / N, n = idx % N;
  Wt[(size_t)n * K + k] = (bf16)W[idx];
}

// ---------------- GEMM1: h1 = relu(feat @ w1t^T + b1), BM=64 BN=256 ----------------
__global__ __launch_bounds__(256)
void mfma_gemm1(const float* __restrict__ A, const bf16* __restrict__ Bt,
                const float* __restrict__ bias, bf16* __restrict__ C, int M) {
  __shared__ bf16 As[64][40];
  __shared__ bf16 Bs[256][40];
  const int tid  = threadIdx.x;
  const int lane = tid & 63;
  const int wave = tid >> 6;       // n-quarter (64 cols each)
  const int row0 = blockIdx.x * 64;
  const int l15  = lane & 15;
  const int quad = lane >> 4;

  f32x4 acc[4][4] = {};

  for (int k0 = 0; k0 < FIN; k0 += 32) {
#pragma unroll
    for (int i = 0; i < 2; ++i) {
      int idx = tid + i * 256;          // 0..511
      int r = idx >> 3, c4 = idx & 7;   // row 0..63, float4-col 0..7
      int gr = row0 + r;
      float4 v = make_float4(0.f, 0.f, 0.f, 0.f);
      if (gr < M) v = *(const float4*)&A[(size_t)gr * FIN + k0 + c4 * 4];
      bf16x4 b;
      b[0] = (bf16)v.x; b[1] = (bf16)v.y; b[2] = (bf16)v.z; b[3] = (bf16)v.w;
      *(bf16x4*)&As[r][c4 * 4] = b;
    }
#pragma unroll
    for (int i = 0; i < 4; ++i) {
      int idx = tid + i * 256;           // 0..1023
      int nrow = idx >> 2, k16 = idx & 3;
      bf16x8 v = *(const bf16x8*)&Bt[(size_t)nrow * FIN + k0 + k16 * 8];
      *(bf16x8*)&Bs[nrow][k16 * 8] = v;
    }
    __syncthreads();

    bf16x8 af[4], bfr[4];
#pragma unroll
    for (int mt = 0; mt < 4; ++mt)
      af[mt] = *(const bf16x8*)&As[mt * 16 + l15][quad * 8];
#pragma unroll
    for (int nt = 0; nt < 4; ++nt)
      bfr[nt] = *(const bf16x8*)&Bs[wave * 64 + nt * 16 + l15][quad * 8];
#pragma unroll
    for (int mt = 0; mt < 4; ++mt)
#pragma unroll
      for (int nt = 0; nt < 4; ++nt)
        acc[mt][nt] = __builtin_amdgcn_mfma_f32_16x16x32_bf16(af[mt], bfr[nt],
                                                              acc[mt][nt], 0, 0, 0);
    __syncthreads();
  }

#pragma unroll
  for (int nt = 0; nt < 4; ++nt) {
    int gc = wave * 64 + nt * 16 + l15;
    float bv = bias[gc];
#pragma unroll
    for (int mt = 0; mt < 4; ++mt)
#pragma unroll
      for (int r = 0; r < 4; ++r) {
        int gr = row0 + mt * 16 + quad * 4 + r;
        if (gr < M) {
          float v = fmaxf(acc[mt][nt][r] + bv, 0.f);
          C[(size_t)gr * HID + gc] = (bf16)v;
        }
      }
  }
}

// ---------------- GEMM2: g0 = norm .* (h1 @ w2t^T + b2), BM=128 BN=64 ----------------
__global__ __launch_bounds__(256)
void mfma_gemm2(const bf16* __restrict__ A, const bf16* __restrict__ Bt,
                const float* __restrict__ bias, const float* __restrict__ norm,
                bf16* __restrict__ g0, int M) {
  __shared__ bf16 As[128][40];
  __shared__ bf16 Bs[64][40];
  const int tid  = threadIdx.x;
  const int lane = tid & 63;
  const int wave = tid >> 6;
  const int wm = wave >> 1;
  const int wn = wave & 1;
  const int row0 = blockIdx.x * 128;
  const int l15  = lane & 15;
  const int quad = lane >> 4;

  f32x4 acc[4][2] = {};

  for (int k0 = 0; k0 < HID; k0 += 32) {
#pragma unroll
    for (int i = 0; i < 2; ++i) {
      int idx = tid + i * 256;
      int r = idx >> 2, k16 = idx & 3;
      int gr = row0 + r;
      bf16x8 v = {};
      if (gr < M) v = *(const bf16x8*)&A[(size_t)gr * HID + k0 + k16 * 8];
      *(bf16x8*)&As[r][k16 * 8] = v;
    }
    {
      int nrow = tid >> 2, k16 = tid & 3;
      bf16x8 v = *(const bf16x8*)&Bt[(size_t)nrow * HID + k0 + k16 * 8];
      *(bf16x8*)&Bs[nrow][k16 * 8] = v;
    }
    __syncthreads();

    bf16x8 af[4], bfr[2];
#pragma unroll
    for (int mt = 0; mt < 4; ++mt)
      af[mt] = *(const bf16x8*)&As[wm * 64 + mt * 16 + l15][quad * 8];
#pragma unroll
    for (int nt = 0; nt < 2; ++nt)
      bfr[nt] = *(const bf16x8*)&Bs[wn * 32 + nt * 16 + l15][quad * 8];
#pragma unroll
    for (int mt = 0; mt < 4; ++mt)
#pragma unroll
      for (int nt = 0; nt < 2; ++nt)
        acc[mt][nt] = __builtin_amdgcn_mfma_f32_16x16x32_bf16(af[mt], bfr[nt],
                                                              acc[mt][nt], 0, 0, 0);
    __syncthreads();
  }

#pragma unroll
  for (int nt = 0; nt < 2; ++nt) {
    int gc = wn * 32 + nt * 16 + l15;
    float bv = bias[gc];
#pragma unroll
    for (int mt = 0; mt < 4; ++mt)
#pragma unroll
      for (int r = 0; r < 4; ++r) {
        int gr = row0 + wm * 64 + mt * 16 + quad * 4 + r;
        if (gr < M) {
          float v = acc[mt][nt][r] + bv;
          g0[(size_t)gr * NCLS + gc] = (bf16)(norm[gr] * v);
        }
      }
  }
}

// ---------------- CSR build: bucketed two-pass, part-major col regions ----------------
__global__ __launch_bounds__(256)
void bucket_pass1(const int* __restrict__ src, const int* __restrict__ dst,
                  unsigned* __restrict__ bcnt, unsigned* __restrict__ bdata, int E) {
  int e = blockIdx.x * 256 + threadIdx.x;
  if (e >= E) return;
  int s = src[e], d = dst[e];
  int b = d >> 6;
  unsigned p = atomicAdd(&bcnt[b * 16], 1u);
  bdata[(size_t)b * BCAP + p] = ((unsigned)s << 6) | (unsigned)(d & 63);
}

// Pass 2: per-(dst,part) LDS histogram (64x4 = 256 counters), one wave scans one
// part, one global atomic per (bucket,part) into that part's col region.
// Emits packed start4[node*4+p] = (pos << 8) | cnt  (cnt <= 255: Poisson(8), safe),
// plus norm / rnorm / norm2a.
__global__ __launch_bounds__(256)
void bucket_pass2(const unsigned* __restrict__ bcnt, const unsigned* __restrict__ bdata,
                  unsigned* __restrict__ counter, float* __restrict__ norm,
                  float* __restrict__ rnorm, float* __restrict__ norm2a,
                  unsigned* __restrict__ start4, int* __restrict__ col) {
  __shared__ unsigned lcnt[NPARTS * 64];
  __shared__ unsigned lpos[NPARTS * 64];
  const int b = blockIdx.x;
  const int tid = threadIdx.x;
  const unsigned cnt = bcnt[b * 16];
  const unsigned* data = &bdata[(size_t)b * BCAP];

  lcnt[tid] = 0;
  __syncthreads();
  for (unsigned i = tid; i < cnt; i += 256) {
    unsigned v = data[i];
    unsigned s = v >> 6;
    unsigned p = s / PART_SZ;
    atomicAdd(&lcnt[p * 64 + (v & 63u)], 1u);
  }
  __syncthreads();

  {
    const int lane = tid & 63;
    const int w = tid >> 6;            // wave w handles part w
    unsigned v = lcnt[w * 64 + lane];
    unsigned inc = v;
#pragma unroll
    for (int o = 1; o < 64; o <<= 1) {
      unsigned t = __shfl_up(inc, o, 64);
      if (lane >= o) inc += t;
    }
    unsigned base = 0;
    if (lane == 63) base = atomicAdd(&counter[w * 16], inc);
    base = __shfl(base, 63, 64);
    lpos[w * 64 + lane] = (unsigned)w * PCAP + base + (inc - v);
  }
  __syncthreads();

  if (tid < 64) {
    int g = b * 64 + tid;
    if (g < NNODES) {
      unsigned deg = lcnt[tid] + lcnt[64 + tid] + lcnt[128 + tid] + lcnt[192 + tid];
#pragma unroll
      for (int p = 0; p < NPARTS; ++p)
        start4[(size_t)g * NPARTS + p] = (lpos[p * 64 + tid] << 8) | lcnt[p * 64 + tid];
      float dp1 = (float)(deg + 1u);
      norm[g]   = rsqrtf(dp1);
      rnorm[g]  = sqrtf(dp1);
      norm2a[g] = (1.0f - ALPHA) / dp1;
    }
  }
  __syncthreads();

  for (unsigned i = tid; i < cnt; i += 256) {
    unsigned v = data[i];
    unsigned s = v >> 6;
    unsigned p = s / PART_SZ;
    unsigned pos = atomicAdd(&lpos[p * 64 + (v & 63u)], 1u);
    col[pos] = (int)s;
  }
}

// ---------------- pull propagation on scaled state g = norm.*h ----------------
// g_new = norm2a * (sum_src g[src] + g[self]) + ALPHA * g0
// Phase-partitioned: all (co-resident, simultaneously launched) waves sweep src
// parts r=0..3 in the same order, so at any instant the gather working set is one
// ~3.2 MB part that fits per-XCD L2. col / finalize traffic is nontemporal so it
// doesn't evict the resident part.
__global__ __launch_bounds__(256, 4)
void appnp_pull_parts(const bf16* __restrict__ g, const bf16* __restrict__ g0,
                      const float* __restrict__ norm2a,
                      const unsigned* __restrict__ start4,
                      const int* __restrict__ col, bf16* __restrict__ g_new) {
  const int wid  = __builtin_amdgcn_readfirstlane(blockIdx.x * 4 + ((int)threadIdx.x >> 6));
  const int lane = threadIdx.x & 63;
  const int node0 = wid * NPW;        // grid covers exactly NNODES: no bounds checks

  float acc[NPW];
#pragma unroll
  for (int t = 0; t < NPW; ++t) acc[t] = 0.f;

  for (int r = 0; r < NPARTS; ++r) {
#pragma unroll
    for (int t = 0; t < NPW; ++t) {
      const int node = node0 + t;
      const unsigned sv = start4[(unsigned)node * NPARTS + r];
      unsigned j = sv >> 8;
      const unsigned j1 = j + (sv & 255u);
      float a = 0.f;
      for (; j + 4 <= j1; j += 4) {
        int c0 = __builtin_nontemporal_load(&col[j]);
        int c1 = __builtin_nontemporal_load(&col[j + 1]);
        int c2 = __builtin_nontemporal_load(&col[j + 2]);
        int c3 = __builtin_nontemporal_load(&col[j + 3]);
        float x0 = (float)g[(unsigned)c0 * 64u + lane];
        float x1 = (float)g[(unsigned)c1 * 64u + lane];
        float x2 = (float)g[(unsigned)c2 * 64u + lane];
        float x3 = (float)g[(unsigned)c3 * 64u + lane];
        a += (x0 + x1) + (x2 + x3);
      }
      if (j + 2 <= j1) {
        int c0 = __builtin_nontemporal_load(&col[j]);
        int c1 = __builtin_nontemporal_load(&col[j + 1]);
        a += (float)g[(unsigned)c0 * 64u + lane]
           + (float)g[(unsigned)c1 * 64u + lane];
        j += 2;
      }
      if (j < j1) {
        int c0 = __builtin_nontemporal_load(&col[j]);
        a += (float)g[(unsigned)c0 * 64u + lane];
      }
      acc[t] += a;
    }
  }

#pragma unroll
  for (int t = 0; t < NPW; ++t) {
    const int node = node0 + t;
    const unsigned idx = (unsigned)node * 64u + lane;
    float sv  = (float)__builtin_nontemporal_load(&g[idx]);     // self-loop
    float g0v = (float)__builtin_nontemporal_load(&g0[idx]);
    float a = acc[t] + sv;
    __builtin_nontemporal_store((bf16)fmaf(norm2a[node], a, ALPHA * g0v), &g_new[idx]);
  }
}

// ---------------- log_softmax on h = g .* rnorm ----------------
__global__ __launch_bounds__(256)
void log_softmax_k(const bf16* __restrict__ g, const float* __restrict__ rnorm,
                   float* __restrict__ out, int n) {
  int wave = threadIdx.x >> 6;
  int lane = threadIdx.x & 63;
  int row = blockIdx.x * 4 + wave;
  if (row >= n) return;
  float x = (float)g[(size_t)row * NCLS + lane] * rnorm[row];
  float m = x;
#pragma unroll
  for (int o = 32; o; o >>= 1) m = fmaxf(m, __shfl_xor(m, o, 64));
  float ex = expf(x - m);
  float s = ex;
#pragma unroll
  for (int o = 32; o; o >>= 1) s += __shfl_xor(s, o, 64);
  out[(size_t)row * NCLS + lane] = x - m - logf(s);
}

// ---------------- launch ----------------
extern "C" void kernel_launch(void* const* d_in, const int* in_sizes, int n_in,
                              void* d_out, int out_size, void* d_ws, size_t ws_size,
                              hipStream_t stream) {
  (void)n_in; (void)out_size; (void)ws_size;
  const float* feat = (const float*)d_in[0];
  const float* w1   = (const float*)d_in[1];
  const float* b1   = (const float*)d_in[2];
  const float* w2   = (const float*)d_in[3];
  const float* b2   = (const float*)d_in[4];
  const int*   src  = (const int*)d_in[5];
  const int*   dst  = (const int*)d_in[6];
  const int E = in_sizes[5];
  float* out = (float*)d_out;

  // workspace layout (~101 MB)
  char* ws = (char*)d_ws;
  size_t off = 0;
  float* norm   = (float*)(ws + off);         off += ((size_t)NNODES * 4 + 255) & ~(size_t)255;
  float* rnorm  = (float*)(ws + off);         off += ((size_t)NNODES * 4 + 255) & ~(size_t)255;
  float* norm2a = (float*)(ws + off);         off += ((size_t)NNODES * 4 + 255) & ~(size_t)255;
  unsigned* start4 = (unsigned*)(ws + off);   off += ((size_t)NNODES * NPARTS * 4 + 255) & ~(size_t)255;
  unsigned* counter = (unsigned*)(ws + off);  off += 256;
  bf16* g0 = (bf16*)(ws + off);               off += (size_t)NNODES * NCLS * 2;   // 12.8 MB
  // X region (51.2 MB): h1b [N][HID] bf16 during MLP; pb0/pb1 alias it (written
  // only after GEMM2 consumed h1b).
  char* X = ws + off;                         off += (size_t)NNODES * HID * 2;
  bf16* h1b = (bf16*)X;
  bf16* pb0 = (bf16*)X;
  bf16* pb1 = (bf16*)(X + (size_t)NNODES * NCLS * 2);
  int*  col = (int*)(ws + off);               off += ((size_t)NPARTS * PCAP * 4 + 255) & ~(size_t)255; // 12.9 MB
  unsigned* bcnt  = (unsigned*)(ws + off);    off += ((size_t)NBUCK * 16 * 4 + 255) & ~(size_t)255;
  unsigned* bdata = (unsigned*)(ws + off);    off += (size_t)NBUCK * BCAP * 4;     // 19.2 MB
  bf16* w1t = (bf16*)(ws + off);              off += ((size_t)HID * FIN * 2 + 255) & ~(size_t)255;
  bf16* w2t = (bf16*)(ws + off);              off += ((size_t)NCLS * HID * 2 + 255) & ~(size_t)255;

  // ---- CSR pass 1 ----
  hipMemsetAsync(bcnt, 0, (size_t)NBUCK * 16 * 4, stream);
  hipMemsetAsync(counter, 0, 256, stream);
  bucket_pass1<<<(E + 255) / 256, 256, 0, stream>>>(src, dst, bcnt, bdata, E);

  // ---- weight transpose/convert (tiny) ----
  transpose_bf16<<<(FIN * HID + 255) / 256, 256, 0, stream>>>(w1, w1t, FIN, HID);
  transpose_bf16<<<(HID * NCLS + 255) / 256, 256, 0, stream>>>(w2, w2t, HID, NCLS);

  // ---- GEMM1 (A fetched once) ----
  mfma_gemm1<<<(NNODES + 63) / 64, 256, 0, stream>>>(feat, w1t, b1, h1b, NNODES);

  // ---- CSR pass 2 (norm needed by GEMM2 epilogue) ----
  bucket_pass2<<<NBUCK, 256, 0, stream>>>(bcnt, bdata, counter, norm, rnorm,
                                          norm2a, start4, col);

  // ---- GEMM2 with fused norm-scaling: writes g0 = norm .* h0 ----
  mfma_gemm2<<<(NNODES + 127) / 128, 256, 0, stream>>>(h1b, w2t, b2, norm, g0, NNODES);

  // ---- APPNP propagation: phase-partitioned pull ----
  const bf16* cur = g0;
  bf16* bufs[2] = {pb0, pb1};
  for (int k = 0; k < KSTEPS; ++k) {
    bf16* nxt = bufs[k & 1];
    appnp_pull_parts<<<PROPB, 256, 0, stream>>>(cur, g0, norm2a, start4, col, nxt);
    cur = nxt;
  }

  // ---- log_softmax (unscale by rnorm) ----
  log_softmax_k<<<(NNODES + 3) / 4, 256, 0, stream>>>(cur, rnorm, out, NNODES);
}